// Round 12
// baseline (308.452 us; speedup 1.0000x reference)
//
#include <hip/hip_runtime.h>
#include <hip/hip_bf16.h>
#include <math.h>

#define Bn 4096
#define Dd 768
#define SC2 28.85390081777927f   // 20 * log2(e): logits kept in base-2 domain
#define EPSF 1e-6f
#define DG 4.8516519541e8f       // expf(20.0f): exact exp_ori diagonal

// ws layout (4-byte elements)
#define O_S      0        // 3*4096 row sums (ori_nodiag, gen, aug)
#define O_SMOA   12288    // same-masked (ori_nodiag + aug) sums
#define O_SMG    16384    // same-masked gen sums
#define ZERO_F   20480    // floats to zero (covers all atomic sums)
#define O_P      20480    // uint: total pairs (= sum cnt^2)
#define O_RM     20608    // uint2[4096]: {tg | rank<<8, rowSlotBase}
#define LIST_OFF   262144      // byte offset: LCAP uint4 pair entries {row,x0,x1,x2}
#define LCAP       (1u << 19)
#define NB_OFF     33554432    // byte offset: bf16 normalized rows on|gn|an

typedef __attribute__((ext_vector_type(8))) short sh8;
typedef __attribute__((ext_vector_type(4))) float f32x4;

static __device__ __forceinline__ unsigned short f2b(float f) {
    unsigned int u = __float_as_uint(f);
    unsigned int r = (u + 0x7fffu + ((u >> 16) & 1u)) >> 16;  // RNE
    return (unsigned short)r;
}

// ---- normalize rows (blocks x<4096) + class sort (block x==4096,y==0) ----
__global__ void norm_sort_kernel(const float* f0, const float* f1, const float* f2,
                                 unsigned short* nb, const int* tg, unsigned int* I,
                                 float* out) {
    int r = blockIdx.x, m = blockIdx.y, tid = threadIdx.x;
    if (r == Bn) {
        if (m != 0) return;
        // ---- sort body (256 threads) ----
        float* F = (float*)I;
        __shared__ unsigned int h[128], pb[128], cur[128];
        for (int e = tid; e < ZERO_F; e += 256) F[e] = 0.f;
        if (tid == 0) { out[0] = 0.f; out[1] = 0.f; }
        if (tid < 128) { h[tid] = 0; cur[tid] = 0; }
        __syncthreads();
        for (int e = tid; e < Bn; e += 256) atomicAdd(&h[tg[e]], 1u);
        __syncthreads();
        if (tid < 128) pb[tid] = h[tid] * h[tid];
        __syncthreads();
        for (int s = 1; s < 128; s <<= 1) {
            unsigned int b = 0;
            if (tid < 128 && tid >= s) b = pb[tid - s];
            __syncthreads();
            if (tid < 128) pb[tid] += b;
            __syncthreads();
        }
        if (tid == 127) I[O_P] = pb[127];
        uint2* RM = (uint2*)(I + O_RM);
        for (int e = tid; e < Bn; e += 256) {
            int c = tg[e];
            unsigned int rk = atomicAdd(&cur[c], 1u);
            unsigned int n = h[c];
            RM[e] = make_uint2((unsigned)c | (rk << 8), (pb[c] - n * n) + rk * n);
        }
        return;
    }
    const float* src = (m == 0 ? f0 : (m == 1 ? f1 : f2)) + (size_t)r * Dd;
    float x0 = src[tid], x1 = src[tid + 256], x2 = src[tid + 512];
    float v = x0 * x0 + x1 * x1 + x2 * x2;
    #pragma unroll
    for (int off = 1; off < 64; off <<= 1) v += __shfl_xor(v, off);
    __shared__ float wr[4];
    if ((tid & 63) == 0) wr[tid >> 6] = v;
    __syncthreads();
    float inv = rsqrtf(wr[0] + wr[1] + wr[2] + wr[3]);
    unsigned short* dst = nb + ((size_t)m * Bn + r) * Dd;
    dst[tid] = f2b(x0 * inv);
    dst[tid + 256] = f2b(x1 * inv);
    dst[tid + 512] = f2b(x2 * inv);
}

// ===== R24: LDS-FREE, BARRIER-FREE K-loop — frags direct from L2 ==========
// Evidence chain: R16-R23 pinned MfmaUtil at 27-29% through every staging/
// sync/occupancy variant that kept the barrier-lockstep LDS pipeline; the
// unified reg file (192 AGPR acc + 128 VGPR = ~320/wave) caps residency at
// ~1.65 waves/SIMD, so the {stage->barrier->read->MFMA} phases serialize
// per wave with nothing to fill gaps. R19's n-owned XCD map makes A/B
// panels L2-RESIDENT (FETCH 40MB ~= ideal, verified) -> the LDS round-trip
// is unnecessary. This kernel reads MFMA fragments DIRECTLY from L2:
// per kt, 16 independent global_load_dwordx4 (16 rows x 64B contiguous
// per instr) + 48 MFMAs. NO __shared__, NO __syncthreads, NO gl_lds, NO
// swizzle. Waves fully decoupled; compiler's counted-vmcnt pipelining
// (m131) hides L2 latency under MFMA; setprio(1) on MFMA clusters (T5
// pays in desynced regime, m191). Pipe budget: L2 ~2.75GB -> 34-40us,
// matrix 37us -> ceiling ~50-70us vs 112 now.
__launch_bounds__(256, 2)
__global__ void gemm_rowsum(const unsigned short* nb, char* ws) {
    float* F = (float*)ws;
    const unsigned int* I = (const unsigned int*)ws;
    const uint2* RM = (const uint2*)(I + O_RM);
    int bid = blockIdx.x;
    int xcd = bid & 7, local = bid >> 3;                // 8 XCDs x 128 tiles
    int n0 = (xcd * 4 + (local & 3)) * 128;             // 4 n-panels per XCD (B L2-resident)
    int m0 = (local >> 2) * 128;                        // n-inner, m-major
    int tid = threadIdx.x, lane = tid & 63, wave = tid >> 6;
    int wm = (wave >> 1) * 64, wn = (wave & 1) * 64;    // 2x2 waves, 64x64/wave/z
    int lid = lane & 15, q = lane >> 4;

    // per-lane fragment base pointers: row = base + lid (+i*16 per frag),
    // k-chunk = q*8 elements. Each 64-lane load: 16 rows x 64B contiguous.
    const unsigned short* pA  = nb + (size_t)(m0 + wm + lid) * Dd + q * 8;
    const unsigned short* pB0 = nb + (size_t)(n0 + wn + lid) * Dd + q * 8;
    const unsigned short* pB1 = pB0 + (size_t)Bn * Dd;
    const unsigned short* pB2 = pB1 + (size_t)Bn * Dd;

    f32x4 a0[4][4] = {}, a1[4][4] = {}, a2[4][4] = {};

    for (int kt = 0; kt < 24; ++kt) {
        int ko = kt * 32;
        sh8 af[4], bf0[4], bf1[4], bf2[4];
        #pragma unroll
        for (int i = 0; i < 4; ++i)
            af[i] = *(const sh8*)(pA + (size_t)i * 16 * Dd + ko);
        #pragma unroll
        for (int j = 0; j < 4; ++j)
            bf0[j] = *(const sh8*)(pB0 + (size_t)j * 16 * Dd + ko);
        #pragma unroll
        for (int j = 0; j < 4; ++j)
            bf1[j] = *(const sh8*)(pB1 + (size_t)j * 16 * Dd + ko);
        #pragma unroll
        for (int j = 0; j < 4; ++j)
            bf2[j] = *(const sh8*)(pB2 + (size_t)j * 16 * Dd + ko);
        __builtin_amdgcn_s_setprio(1);
        #pragma unroll
        for (int i = 0; i < 4; ++i)
            #pragma unroll
            for (int j = 0; j < 4; ++j)
                a0[i][j] = __builtin_amdgcn_mfma_f32_16x16x32_bf16(af[i], bf0[j], a0[i][j], 0, 0, 0);
        #pragma unroll
        for (int i = 0; i < 4; ++i)
            #pragma unroll
            for (int j = 0; j < 4; ++j)
                a1[i][j] = __builtin_amdgcn_mfma_f32_16x16x32_bf16(af[i], bf1[j], a1[i][j], 0, 0, 0);
        #pragma unroll
        for (int i = 0; i < 4; ++i)
            #pragma unroll
            for (int j = 0; j < 4; ++j)
                a2[i][j] = __builtin_amdgcn_mfma_f32_16x16x32_bf16(af[i], bf2[j], a2[i][j], 0, 0, 0);
        __builtin_amdgcn_s_setprio(0);
    }

    // ---- fused epilogue: 3 row sums, 2 masked sums, single uint4 pair store
    uint2 rmc[4];
    #pragma unroll
    for (int j = 0; j < 4; ++j) rmc[j] = RM[n0 + wn + j * 16 + lid];
    uint4* Lq = (uint4*)(ws + LIST_OFF);
    #pragma unroll
    for (int i = 0; i < 4; ++i)
        #pragma unroll
        for (int reg = 0; reg < 4; ++reg) {
            int grow = m0 + wm + i * 16 + q * 4 + reg;
            uint2 rm = RM[grow];
            unsigned int trow = rm.x & 255u, rsb = rm.y;
            float rs0 = 0.f, rs1 = 0.f, rs2 = 0.f, msOA = 0.f, msG = 0.f;
            #pragma unroll
            for (int j = 0; j < 4; ++j) {
                int gcol = n0 + wn + j * 16 + lid;
                float x0 = a0[i][j][reg] * SC2;
                float x1 = a1[i][j][reg] * SC2;
                float x2 = a2[i][j][reg] * SC2;
                float e0 = exp2f(x0);
                float e1 = exp2f(x1);
                float e2 = exp2f(x2);
                if (gcol == grow) e0 = 0.f;   // ori diagonal excluded from sums
                rs0 += e0; rs1 += e1; rs2 += e2;
                if ((rmc[j].x & 255u) == trow) {
                    msOA += e0 + e2;
                    msG  += e1;
                    unsigned int slot = rsb + (rmc[j].x >> 8);
                    if (slot < LCAP)
                        Lq[slot] = make_uint4((unsigned)grow, __float_as_uint(x0),
                                              __float_as_uint(x1), __float_as_uint(x2));
                }
            }
            #pragma unroll
            for (int off = 1; off < 16; off <<= 1) {
                rs0 += __shfl_xor(rs0, off);
                rs1 += __shfl_xor(rs1, off);
                rs2 += __shfl_xor(rs2, off);
                msOA += __shfl_xor(msOA, off);
                msG  += __shfl_xor(msG, off);
            }
            if (lid == 0) {
                atomicAdd(&F[O_S + grow], rs0);
                atomicAdd(&F[O_S + Bn + grow], rs1);
                atomicAdd(&F[O_S + 2 * Bn + grow], rs2);
                atomicAdd(&F[O_SMOA + grow], msOA);
                atomicAdd(&F[O_SMG + grow], msG);
            }
        }
}

// ---- flat loss pass: inline denominators, scaled atomic into d_out ----
__launch_bounds__(256)
__global__ void loss_kernel(char* ws, float* out) {
    float* F = (float*)ws;
    const unsigned int* I = (const unsigned int*)ws;
    const uint4* L = (const uint4*)(ws + LIST_OFF);
    unsigned int n = I[O_P]; if (n > LCAP) n = LCAP;
    float a0 = 0.f, a1 = 0.f;
    unsigned int stride = gridDim.x * 256;
    for (unsigned int idx = blockIdx.x * 256 + threadIdx.x; idx < n; idx += stride) {
        uint4 en = L[idx];
        int i = (int)en.x;
        float son = F[O_S + i], sgen = F[O_S + Bn + i], saug = F[O_S + 2 * Bn + i];
        float dco = (son + saug - F[O_SMOA + i]) + sgen + EPSF;
        float dad = (sgen - F[O_SMG + i]) + saug + son + DG + EPSF;
        float eo = exp2f(__uint_as_float(en.y));
        float eg = exp2f(__uint_as_float(en.z));
        float ea = exp2f(__uint_as_float(en.w));
        a0 += -__logf(eg / (eg + dad) + EPSF);
        a1 += -__logf(eo / (eo + dco) + EPSF) - __logf(ea / (ea + dco) + EPSF);
    }
    #pragma unroll
    for (int off = 1; off < 64; off <<= 1) { a0 += __shfl_xor(a0, off); a1 += __shfl_xor(a1, off); }
    __shared__ float r0[4], r1[4];
    int tid = threadIdx.x;
    if ((tid & 63) == 0) { r0[tid >> 6] = a0; r1[tid >> 6] = a1; }
    __syncthreads();
    if (tid == 0) {
        atomicAdd(&out[0], (r0[0] + r0[1] + r0[2] + r0[3]) * (1.0f / Bn));  // ad_loss
        atomicAdd(&out[1], (r1[0] + r1[1] + r1[2] + r1[3]) * (1.0f / Bn));  // co_loss
    }
}

extern "C" void kernel_launch(void* const* d_in, const int* in_sizes, int n_in,
                              void* d_out, int out_size, void* d_ws, size_t ws_size,
                              hipStream_t stream) {
    const float* f0 = (const float*)d_in[0];
    const float* f1 = (const float*)d_in[1];
    const float* f2 = (const float*)d_in[2];
    const int* tg = (const int*)d_in[3];
    char* ws = (char*)d_ws;
    unsigned int* I = (unsigned int*)d_ws;
    unsigned short* nb = (unsigned short*)(ws + NB_OFF);
    float* out = (float*)d_out;

    norm_sort_kernel<<<dim3(Bn + 1, 3), 256, 0, stream>>>(f0, f1, f2, nb, tg, I, out);
    gemm_rowsum<<<dim3(1024), 256, 0, stream>>>(nb, ws);
    loss_kernel<<<256, 256, 0, stream>>>(ws, out);
}

// Round 13
// 226.201 us; speedup vs baseline: 1.3636x; 1.3636x over previous
//
#include <hip/hip_runtime.h>
#include <hip/hip_bf16.h>
#include <math.h>

#define Bn 4096
#define Dd 768
#define SC2 28.85390081777927f   // 20 * log2(e): logits kept in base-2 domain
#define EPSF 1e-6f
#define DG 4.8516519541e8f       // expf(20.0f): exact exp_ori diagonal

// ws layout (4-byte elements)
#define O_S      0        // 3*4096 row sums (ori_nodiag, gen, aug)
#define O_SMOA   12288    // same-masked (ori_nodiag + aug) sums
#define O_SMG    16384    // same-masked gen sums
#define ZERO_F   20480    // floats to zero (covers all atomic sums)
#define O_P      20480    // uint: total pairs (= sum cnt^2)
#define O_RM     20608    // uint2[4096]: {tg | rank<<8, rowSlotBase}
#define LIST_OFF   262144      // byte offset: LCAP uint4 pair entries {row,x0,x1,x2}
#define LCAP       (1u << 19)
#define NB_OFF     33554432    // byte offset: bf16 normalized rows on|gn|an

typedef __attribute__((ext_vector_type(8))) short sh8;
typedef __attribute__((ext_vector_type(4))) float f32x4;

#define AS1 __attribute__((address_space(1)))
#define AS3 __attribute__((address_space(3)))

static __device__ __forceinline__ void gl_lds16(const void* g, void* l) {
    __builtin_amdgcn_global_load_lds((const AS1 void*)g, (AS3 void*)l, 16, 0, 0);
}

static __device__ __forceinline__ unsigned short f2b(float f) {
    unsigned int u = __float_as_uint(f);
    unsigned int r = (u + 0x7fffu + ((u >> 16) & 1u)) >> 16;  // RNE
    return (unsigned short)r;
}

// ---- normalize rows (blocks x<4096) + class sort (block x==4096,y==0) ----
__global__ void norm_sort_kernel(const float* f0, const float* f1, const float* f2,
                                 unsigned short* nb, const int* tg, unsigned int* I,
                                 float* out) {
    int r = blockIdx.x, m = blockIdx.y, tid = threadIdx.x;
    if (r == Bn) {
        if (m != 0) return;
        // ---- sort body (256 threads) ----
        float* F = (float*)I;
        __shared__ unsigned int h[128], pb[128], cur[128];
        for (int e = tid; e < ZERO_F; e += 256) F[e] = 0.f;
        if (tid == 0) { out[0] = 0.f; out[1] = 0.f; }
        if (tid < 128) { h[tid] = 0; cur[tid] = 0; }
        __syncthreads();
        for (int e = tid; e < Bn; e += 256) atomicAdd(&h[tg[e]], 1u);
        __syncthreads();
        if (tid < 128) pb[tid] = h[tid] * h[tid];
        __syncthreads();
        for (int s = 1; s < 128; s <<= 1) {
            unsigned int b = 0;
            if (tid < 128 && tid >= s) b = pb[tid - s];
            __syncthreads();
            if (tid < 128) pb[tid] += b;
            __syncthreads();
        }
        if (tid == 127) I[O_P] = pb[127];
        uint2* RM = (uint2*)(I + O_RM);
        for (int e = tid; e < Bn; e += 256) {
            int c = tg[e];
            unsigned int rk = atomicAdd(&cur[c], 1u);
            unsigned int n = h[c];
            RM[e] = make_uint2((unsigned)c | (rk << 8), (pb[c] - n * n) + rk * n);
        }
        return;
    }
    const float* src = (m == 0 ? f0 : (m == 1 ? f1 : f2)) + (size_t)r * Dd;
    float x0 = src[tid], x1 = src[tid + 256], x2 = src[tid + 512];
    float v = x0 * x0 + x1 * x1 + x2 * x2;
    #pragma unroll
    for (int off = 1; off < 64; off <<= 1) v += __shfl_xor(v, off);
    __shared__ float wr[4];
    if ((tid & 63) == 0) wr[tid >> 6] = v;
    __syncthreads();
    float inv = rsqrtf(wr[0] + wr[1] + wr[2] + wr[3]);
    unsigned short* dst = nb + ((size_t)m * Bn + r) * Dd;
    dst[tid] = f2b(x0 * inv);
    dst[tid + 256] = f2b(x1 * inv);
    dst[tid + 512] = f2b(x2 * inv);
}

// ===== R25: ONE WAVE PER BLOCK — barrier-free with wave-private LDS =======
// Constraint triangle from R16-R24: (a) LDS staging required (R24 direct-L2
// frags = sector-request-bound, 13.9% util); (b) __syncthreads lockstep
// caps util at 27-29% regardless of buffering (R16/18/19/20/23 invariant);
// (c) pipeline depth paid in LDS/regs kills residency (R17/R18/R21).
// Single-wave blocks satisfy all three: the wave stages its OWN 16KB tile
// (coalesced gl_lds), waits vmcnt(0) on itself, NO barrier exists. Waves
// on a CU fully desynced -> one wave's load/read phase overlaps its SIMD
// partner's MFMA phase. In-wave single-buffer pipelining is race-free:
// after last ds_read of tile t (+lgkmcnt), issue tile t+1 loads; they land
// under z2's MFMAs. Tile 64x64x3z keeps R19's proven 16:48 read:MFMA
// ratio; acc 192 AGPR + z-sequential frags (48 VGPR) + addr ~ 250 regs
// fits __launch_bounds__(64,2) -> 2 waves/SIMD, 8 blocks/CU, 128KB LDS.
// Frozen: n-owned XCD map (64-wide: xcd owns 8 n-tiles, B L2-resident),
// chunk^((row>>1)&3) swizzle (same bank math at 64B rows -> 2/bank, free),
// fused epilogue, norm/sort/loss.
__launch_bounds__(64, 2)
__global__ void gemm_rowsum(const unsigned short* nb, char* ws) {
    float* F = (float*)ws;
    const unsigned int* I = (const unsigned int*)ws;
    const uint2* RM = (const uint2*)(I + O_RM);
    int bid = blockIdx.x;
    int xcd = bid & 7, local = bid >> 3;            // 8 XCDs x 512 tiles
    int n0 = (xcd * 8 + (local & 7)) * 64;          // 8 64-wide n-tiles/XCD
    int m0 = (local >> 3) * 64;                     // n-inner, m-major
    int lane = threadIdx.x;
    int lid = lane & 15, q = lane >> 4;
    __shared__ __align__(16) unsigned short L[4][2048];   // A,B0,B1,B2 = 16 KB

    // staging: lane -> (row = lane>>2, chunk = lane&3); each gl_lds covers
    // 16 rows x 64B; 4 row-groups per region ((row+16)>>1 &3 unchanged).
    // LDS linear dest, source chunk pre-swizzled (both-sides-or-neither).
    int row0 = lane >> 2, ch = lane & 3;
    int cs = (ch ^ ((row0 >> 1) & 3)) * 8;
    const unsigned short* gA  = nb + (size_t)(m0 + row0) * Dd + cs;
    const unsigned short* gB0 = nb + (size_t)(n0 + row0) * Dd + cs;
    const unsigned short* gB1 = gB0 + (size_t)Bn * Dd;
    const unsigned short* gB2 = gB1 + (size_t)Bn * Dd;

    // frag-read swizzle: row = i*16+lid -> (row>>1)&3 == (lid>>1)&3
    int cswz = (q ^ ((lid >> 1) & 3)) * 8;

    f32x4 a0[4][4] = {}, a1[4][4] = {}, a2[4][4] = {};

#define STG(kt) { int ko = (kt) * 32; \
    _Pragma("unroll") \
    for (int g = 0; g < 4; ++g) { \
        gl_lds16(gA  + (size_t)g * 16 * Dd + ko, &L[0][g * 512]); \
        gl_lds16(gB0 + (size_t)g * 16 * Dd + ko, &L[1][g * 512]); \
        gl_lds16(gB1 + (size_t)g * 16 * Dd + ko, &L[2][g * 512]); \
        gl_lds16(gB2 + (size_t)g * 16 * Dd + ko, &L[3][g * 512]); } }

    STG(0);
    for (int kt = 0; kt < 24; ++kt) {
        // own loads of tile kt are the only outstanding VMEM: wait, read.
        asm volatile("s_waitcnt vmcnt(0)" ::: "memory");
        __builtin_amdgcn_sched_barrier(0);
        sh8 af[4], bfA[4], bfB[4];
        #pragma unroll
        for (int i = 0; i < 4; ++i)
            af[i] = *(const sh8*)&L[0][(i * 16 + lid) * 32 + cswz];
        #pragma unroll
        for (int j = 0; j < 4; ++j)
            bfA[j] = *(const sh8*)&L[1][(j * 16 + lid) * 32 + cswz];
        __builtin_amdgcn_s_setprio(1);
        #pragma unroll
        for (int i = 0; i < 4; ++i)
            #pragma unroll
            for (int j = 0; j < 4; ++j)
                a0[i][j] = __builtin_amdgcn_mfma_f32_16x16x32_bf16(af[i], bfA[j], a0[i][j], 0, 0, 0);
        __builtin_amdgcn_s_setprio(0);
        #pragma unroll
        for (int j = 0; j < 4; ++j)
            bfB[j] = *(const sh8*)&L[2][(j * 16 + lid) * 32 + cswz];
        __builtin_amdgcn_s_setprio(1);
        #pragma unroll
        for (int i = 0; i < 4; ++i)
            #pragma unroll
            for (int j = 0; j < 4; ++j)
                a1[i][j] = __builtin_amdgcn_mfma_f32_16x16x32_bf16(af[i], bfB[j], a1[i][j], 0, 0, 0);
        __builtin_amdgcn_s_setprio(0);
        #pragma unroll
        for (int j = 0; j < 4; ++j)
            bfA[j] = *(const sh8*)&L[3][(j * 16 + lid) * 32 + cswz];   // reuse bfA regs
        // all 16 ds_reads of tile kt are issued; drain them, then issue
        // tile kt+1 loads into the SAME buffer (safe: single wave, reads
        // retired). Loads fly under z2's MFMAs + next vmcnt wait.
        asm volatile("s_waitcnt lgkmcnt(0)" ::: "memory");
        __builtin_amdgcn_sched_barrier(0);
        if (kt < 23) STG(kt + 1);
        __builtin_amdgcn_s_setprio(1);
        #pragma unroll
        for (int i = 0; i < 4; ++i)
            #pragma unroll
            for (int j = 0; j < 4; ++j)
                a2[i][j] = __builtin_amdgcn_mfma_f32_16x16x32_bf16(af[i], bfA[j], a2[i][j], 0, 0, 0);
        __builtin_amdgcn_s_setprio(0);
    }

    // ---- fused epilogue: 3 row sums, 2 masked sums, single uint4 pair store
    uint2 rmc[4];
    #pragma unroll
    for (int j = 0; j < 4; ++j) rmc[j] = RM[n0 + j * 16 + lid];
    uint4* Lq = (uint4*)(ws + LIST_OFF);
    #pragma unroll
    for (int i = 0; i < 4; ++i)
        #pragma unroll
        for (int reg = 0; reg < 4; ++reg) {
            int grow = m0 + i * 16 + q * 4 + reg;
            uint2 rm = RM[grow];
            unsigned int trow = rm.x & 255u, rsb = rm.y;
            float rs0 = 0.f, rs1 = 0.f, rs2 = 0.f, msOA = 0.f, msG = 0.f;
            #pragma unroll
            for (int j = 0; j < 4; ++j) {
                int gcol = n0 + j * 16 + lid;
                float x0 = a0[i][j][reg] * SC2;
                float x1 = a1[i][j][reg] * SC2;
                float x2 = a2[i][j][reg] * SC2;
                float e0 = exp2f(x0);
                float e1 = exp2f(x1);
                float e2 = exp2f(x2);
                if (gcol == grow) e0 = 0.f;   // ori diagonal excluded from sums
                rs0 += e0; rs1 += e1; rs2 += e2;
                if ((rmc[j].x & 255u) == trow) {
                    msOA += e0 + e2;
                    msG  += e1;
                    unsigned int slot = rsb + (rmc[j].x >> 8);
                    if (slot < LCAP)
                        Lq[slot] = make_uint4((unsigned)grow, __float_as_uint(x0),
                                              __float_as_uint(x1), __float_as_uint(x2));
                }
            }
            #pragma unroll
            for (int off = 1; off < 16; off <<= 1) {
                rs0 += __shfl_xor(rs0, off);
                rs1 += __shfl_xor(rs1, off);
                rs2 += __shfl_xor(rs2, off);
                msOA += __shfl_xor(msOA, off);
                msG  += __shfl_xor(msG, off);
            }
            if (lid == 0) {
                atomicAdd(&F[O_S + grow], rs0);
                atomicAdd(&F[O_S + Bn + grow], rs1);
                atomicAdd(&F[O_S + 2 * Bn + grow], rs2);
                atomicAdd(&F[O_SMOA + grow], msOA);
                atomicAdd(&F[O_SMG + grow], msG);
            }
        }
}

// ---- flat loss pass: inline denominators, scaled atomic into d_out ----
__launch_bounds__(256)
__global__ void loss_kernel(char* ws, float* out) {
    float* F = (float*)ws;
    const unsigned int* I = (const unsigned int*)ws;
    const uint4* L = (const uint4*)(ws + LIST_OFF);
    unsigned int n = I[O_P]; if (n > LCAP) n = LCAP;
    float a0 = 0.f, a1 = 0.f;
    unsigned int stride = gridDim.x * 256;
    for (unsigned int idx = blockIdx.x * 256 + threadIdx.x; idx < n; idx += stride) {
        uint4 en = L[idx];
        int i = (int)en.x;
        float son = F[O_S + i], sgen = F[O_S + Bn + i], saug = F[O_S + 2 * Bn + i];
        float dco = (son + saug - F[O_SMOA + i]) + sgen + EPSF;
        float dad = (sgen - F[O_SMG + i]) + saug + son + DG + EPSF;
        float eo = exp2f(__uint_as_float(en.y));
        float eg = exp2f(__uint_as_float(en.z));
        float ea = exp2f(__uint_as_float(en.w));
        a0 += -__logf(eg / (eg + dad) + EPSF);
        a1 += -__logf(eo / (eo + dco) + EPSF) - __logf(ea / (ea + dco) + EPSF);
    }
    #pragma unroll
    for (int off = 1; off < 64; off <<= 1) { a0 += __shfl_xor(a0, off); a1 += __shfl_xor(a1, off); }
    __shared__ float r0[4], r1[4];
    int tid = threadIdx.x;
    if ((tid & 63) == 0) { r0[tid >> 6] = a0; r1[tid >> 6] = a1; }
    __syncthreads();
    if (tid == 0) {
        atomicAdd(&out[0], (r0[0] + r0[1] + r0[2] + r0[3]) * (1.0f / Bn));  // ad_loss
        atomicAdd(&out[1], (r1[0] + r1[1] + r1[2] + r1[3]) * (1.0f / Bn));  // co_loss
    }
}

extern "C" void kernel_launch(void* const* d_in, const int* in_sizes, int n_in,
                              void* d_out, int out_size, void* d_ws, size_t ws_size,
                              hipStream_t stream) {
    const float* f0 = (const float*)d_in[0];
    const float* f1 = (const float*)d_in[1];
    const float* f2 = (const float*)d_in[2];
    const int* tg = (const int*)d_in[3];
    char* ws = (char*)d_ws;
    unsigned int* I = (unsigned int*)d_ws;
    unsigned short* nb = (unsigned short*)(ws + NB_OFF);
    float* out = (float*)d_out;

    norm_sort_kernel<<<dim3(Bn + 1, 3), 256, 0, stream>>>(f0, f1, f2, nb, tg, I, out);
    gemm_rowsum<<<dim3(4096), 64, 0, stream>>>(nb, ws);
    loss_kernel<<<256, 256, 0, stream>>>(ws, out);
}